// Round 3
// baseline (84.224 us; speedup 1.0000x reference)
//
#include <hip/hip_runtime.h>

#define D 128
#define NS 16
#define BATCH 16384
#define TILE 32
#define NTB 32   // grid.x: 32 tile-blocks per state + stride loop for safety

typedef __attribute__((ext_vector_type(8))) short short8;
typedef __attribute__((ext_vector_type(4))) float f32x4;

__device__ __forceinline__ unsigned short f2bf(float f) {
  unsigned u = __builtin_bit_cast(unsigned, f);
  u += 0x7FFFu + ((u >> 16) & 1u);   // round-to-nearest-even
  return (unsigned short)(u >> 16);
}

// counts padded to one 128B line per state (R1: shared-line atomics = 48us).
#define CPAD 32

// ---------------------------------------------------------------------------
// prep: blocks [0,128): LDS-staged transpose+convert A/C -> bf16 (At[e][d])
//       blocks [128,192): per-state row lists, block-aggregated atomics
// ---------------------------------------------------------------------------
__global__ __launch_bounds__(256) void prep_kernel(
    const float* __restrict__ A_all, const float* __restrict__ C_all,
    const int* __restrict__ sidx,
    int* __restrict__ counts, unsigned short* __restrict__ lists,
    unsigned short* __restrict__ At, unsigned short* __restrict__ Ct) {
  const int b = blockIdx.x, tid = threadIdx.x;
  if (b < 128) {
    __shared__ float T[32][129];
    const int mat = b >> 6, r = b & 63, s = r >> 2, slab = r & 3;
    const float* in = (mat ? C_all : A_all) + (size_t)s * D * D;
    unsigned short* outp = (mat ? Ct : At) + (size_t)s * D * D;
    const int e0 = slab * 32;
    const int ecol = (tid & 7) * 4;
    const int drow = tid >> 3;
#pragma unroll
    for (int i = 0; i < 4; i++) {
      const int d = drow + 32 * i;
      const float4 v = *(const float4*)(in + (size_t)d * D + e0 + ecol);
      T[ecol + 0][d] = v.x;
      T[ecol + 1][d] = v.y;
      T[ecol + 2][d] = v.z;
      T[ecol + 3][d] = v.w;
    }
    __syncthreads();
    const int e = tid >> 3;
    const int d0 = (tid & 7) * 16;
    unsigned short p[16];
#pragma unroll
    for (int k = 0; k < 16; k++) p[k] = f2bf(T[e][d0 + k]);
    unsigned short* dst = outp + (size_t)(e0 + e) * D + d0;
    *(uint4*)(dst) = *(const uint4*)(p);
    *(uint4*)(dst + 8) = *(const uint4*)(p + 8);
  } else {
    __shared__ int wcnt[4][NS];
    __shared__ int woff[4][NS];
    __shared__ int sbase[NS];
    const int i = (b - 128) * 256 + tid;
    const int s = sidx[i];
    const int lane = tid & 63, w = tid >> 6;
    int myrank = 0;
#pragma unroll 1
    for (int ss = 0; ss < NS; ss++) {
      unsigned long long m = __ballot(s == ss);
      if (s == ss) myrank = (int)__popcll(m & ((1ull << lane) - 1ull));
      if (lane == 0) wcnt[w][ss] = (int)__popcll(m);
    }
    __syncthreads();
    if (tid < NS) {
      const int c0 = wcnt[0][tid], c1 = wcnt[1][tid];
      const int c2 = wcnt[2][tid], c3 = wcnt[3][tid];
      sbase[tid] = atomicAdd(&counts[tid * CPAD], c0 + c1 + c2 + c3);
      woff[0][tid] = 0;
      woff[1][tid] = c0;
      woff[2][tid] = c0 + c1;
      woff[3][tid] = c0 + c1 + c2;
    }
    __syncthreads();
    lists[(size_t)s * BATCH + sbase[s] + woff[w][s] + myrank] = (unsigned short)i;
  }
}

// ---------------------------------------------------------------------------
// main: one block = 32 rows of one state; 4 waves in 2x2 (16 rows x 64 cols).
//  Latency plan: x-gather + At-stage + Ct->reg prefetch ALL issued at t=0;
//  Ct regs land in Ws after the phase-1 sync (no mid-chain global stall).
//  MFMA 16x16x32 bf16 layouts (HW-verified):
//    A: A[m=lane&15][k=(lane>>4)*8+j]   B: B[k=(lane>>4)*8+j][n=lane&15]
//    C/D: col=lane&15, row=(lane>>4)*4+reg
// ---------------------------------------------------------------------------
__global__ __launch_bounds__(256, 3) void ssm_kernel(
    const float* __restrict__ x,
    const int* __restrict__ counts,
    const unsigned short* __restrict__ lists,
    const unsigned short* __restrict__ At,
    const unsigned short* __restrict__ Ct,
    float* __restrict__ out) {
  __shared__ unsigned short Xs[TILE][136];  // X tile (bf16)
  __shared__ unsigned short Hs[TILE][136];  // relu(X@A) tile (bf16)
  __shared__ unsigned short Ws[D][136];     // At, then Ct
  __shared__ int rows[TILE];

  const int s = blockIdx.y;
  const int n = counts[s * CPAD];
  const int tid = threadIdx.x;
  const int lane = tid & 63, w = tid >> 6;
  const int l15 = lane & 15, quad = lane >> 4;
  const int wr = w & 1, wc = w >> 1;  // wave = (row-half, col-half)

  for (int t0 = blockIdx.x; t0 * TILE < n; t0 += NTB) {
    if (t0 != blockIdx.x) __syncthreads();  // block-uniform trip count
    const int row0 = t0 * TILE;
    const int nr = min(TILE, n - row0);
    const size_t lb = (size_t)s * BATCH + row0;

    // ---- Ct prefetch into registers (32 VGPRs; written to Ws after sync) --
    uint4 ctr[8];
    {
      const uint4* g = (const uint4*)(Ct + (size_t)s * D * D);
#pragma unroll
      for (int i = 0; i < 8; i++) ctr[i] = g[i * 256 + tid];
    }

    // ---- stage X (gathered rows, fp32 -> bf16), 8 threads/row ----
    {
      const int r = tid >> 3, q = tid & 7;
      int rid = (r < nr) ? (int)lists[lb + r] : -1;
      if (q == 0) rows[r] = rid;
      unsigned short* xr = &Xs[r][q * 16];
      if (rid >= 0) {
        const float4* src = (const float4*)(x + (size_t)rid * D + q * 16);
#pragma unroll
        for (int i = 0; i < 4; i++) {
          float4 v = src[i];
          ushort4 p;
          p.x = f2bf(v.x); p.y = f2bf(v.y); p.z = f2bf(v.z); p.w = f2bf(v.w);
          *(ushort4*)(xr + i * 4) = p;
        }
      } else {
        ushort4 z; z.x = z.y = z.z = z.w = 0;
#pragma unroll
        for (int i = 0; i < 4; i++) *(ushort4*)(xr + i * 4) = z;
      }
    }
    // ---- stage At[s] -> Ws ----
    {
      const uint4* g = (const uint4*)(At + (size_t)s * D * D);
#pragma unroll
      for (int i = 0; i < 8; i++) {
        const int c = i * 256 + tid;
        *(uint4*)&Ws[c >> 4][(c & 15) * 8] = g[c];
      }
    }
    __syncthreads();

    // ---- phase 1: out1 = X @ A (rows 16*wr.., cols 64*wc..) ----
    f32x4 acc[4];
#pragma unroll
    for (int nb = 0; nb < 4; nb++) acc[nb] = (f32x4){0.f, 0.f, 0.f, 0.f};
#pragma unroll
    for (int kb = 0; kb < 4; kb++) {
      short8 aF = *(const short8*)&Xs[wr * 16 + l15][kb * 32 + quad * 8];
#pragma unroll
      for (int nb = 0; nb < 4; nb++) {
        short8 bF = *(const short8*)&Ws[wc * 64 + nb * 16 + l15][kb * 32 + quad * 8];
        acc[nb] = __builtin_amdgcn_mfma_f32_16x16x32_bf16(aF, bF, acc[nb], 0, 0, 0);
      }
    }
    // relu -> Hs (fresh buffer: safe before the barrier)
#pragma unroll
    for (int nb = 0; nb < 4; nb++)
#pragma unroll
      for (int r = 0; r < 4; r++) {
        float v = acc[nb][r];
        Hs[wr * 16 + quad * 4 + r][wc * 64 + nb * 16 + l15] = f2bf(v > 0.f ? v : 0.f);
      }
    __syncthreads();  // all phase-1 reads of Ws done

    // ---- Ct regs -> Ws ----
#pragma unroll
    for (int i = 0; i < 8; i++) {
      const int c = i * 256 + tid;
      *(uint4*)&Ws[c >> 4][(c & 15) * 8] = ctr[i];
    }
    __syncthreads();

    // ---- phase 2: out = relu(out1) @ C ----
#pragma unroll
    for (int nb = 0; nb < 4; nb++) acc[nb] = (f32x4){0.f, 0.f, 0.f, 0.f};
#pragma unroll
    for (int kb = 0; kb < 4; kb++) {
      short8 aF = *(const short8*)&Hs[wr * 16 + l15][kb * 32 + quad * 8];
#pragma unroll
      for (int nb = 0; nb < 4; nb++) {
        short8 bF = *(const short8*)&Ws[wc * 64 + nb * 16 + l15][kb * 32 + quad * 8];
        acc[nb] = __builtin_amdgcn_mfma_f32_16x16x32_bf16(aF, bF, acc[nb], 0, 0, 0);
      }
    }

    // ---- scatter rows back to global (fp32) ----
#pragma unroll
    for (int r = 0; r < 4; r++) {
      const int rl = wr * 16 + quad * 4 + r;
      if (rl < nr) {
        float* orow = out + (size_t)rows[rl] * D + wc * 64 + l15;
#pragma unroll
        for (int nb = 0; nb < 4; nb++) orow[nb * 16] = acc[nb][r];
      }
    }
  }
}

extern "C" void kernel_launch(void* const* d_in, const int* in_sizes, int n_in,
                              void* d_out, int out_size, void* d_ws, size_t ws_size,
                              hipStream_t stream) {
  const float* x = (const float*)d_in[0];
  const int* sidx = (const int*)d_in[1];
  const float* A_all = (const float*)d_in[2];
  const float* C_all = (const float*)d_in[3];
  float* out = (float*)d_out;

  // ws: counts(2KB padded) | lists(512KB u16) | At(512KB bf16) | Ct(512KB)
  int* counts = (int*)d_ws;
  unsigned short* lists = (unsigned short*)((char*)d_ws + 2048);
  unsigned short* At = (unsigned short*)((char*)d_ws + 2048 + 512 * 1024);
  unsigned short* Ct = At + NS * D * D;

  hipMemsetAsync(counts, 0, 2048, stream);
  prep_kernel<<<192, 256, 0, stream>>>(A_all, C_all, sidx, counts, lists, At, Ct);
  ssm_kernel<<<dim3(NTB, NS), 256, 0, stream>>>(x, counts, lists, At, Ct, out);
}